// Round 10
// baseline (355.914 us; speedup 1.0000x reference)
//
#include <hip/hip_runtime.h>
#include <hip/hip_bf16.h>

// Problem constants: B,T,V,E,U = 256,512,20000,128,128
#define BB 256
#define TT 512
#define VV 20000
#define EE 128
#define UU 128
#define G4 512   // 4*U gate width

typedef _Float16 h2 __attribute__((ext_vector_type(2)));

__device__ __forceinline__ float sigmoid_f(float x) {
    float e = __expf(-x);
    return __builtin_amdgcn_rcpf(1.0f + e);
}
__device__ __forceinline__ float tanh_f(float x) {
    float e = __expf(2.0f * x);
    return 1.0f - 2.0f * __builtin_amdgcn_rcpf(e + 1.0f);
}

// DPP helpers (quad_perm; quads are lane groups 4k..4k+3)
__device__ __forceinline__ int dpp_i(int v, int pat) {
    switch (pat) {
        case 0xB1: return __builtin_amdgcn_mov_dpp(v, 0xB1, 0xF, 0xF, true);
        case 0x4E: return __builtin_amdgcn_mov_dpp(v, 0x4E, 0xF, 0xF, true);
        case 0x00: return __builtin_amdgcn_mov_dpp(v, 0x00, 0xF, 0xF, true);
        case 0x55: return __builtin_amdgcn_mov_dpp(v, 0x55, 0xF, 0xF, true);
        case 0xAA: return __builtin_amdgcn_mov_dpp(v, 0xAA, 0xF, 0xF, true);
        default:   return __builtin_amdgcn_mov_dpp(v, 0xFF, 0xF, 0xF, true);
    }
}
__device__ __forceinline__ float dpp_f(float v, int pat) {
    return __int_as_float(dpp_i(__float_as_int(v), pat));
}
// packed f16 add of a DPP-moved value: mov_dpp + v_pk_add_f16
__device__ __forceinline__ h2 pk_add_dpp(h2 s, int pat) {
    int m = dpp_i(__builtin_bit_cast(int, s), pat);
    return s + __builtin_bit_cast(h2, m);
}

// ---------------------------------------------------------------------------
// Phase 1: projected-token table in GATE-MINOR layout:
//   P2[v][u][g] = sum_e emb[v][e]*K[e][g*128+u] + bias[g*128+u]
// ---------------------------------------------------------------------------
__global__ __launch_bounds__(512, 2) void proj_kernel(
    const float* __restrict__ emb, const float* __restrict__ wk,
    const float* __restrict__ bias, float* __restrict__ P2) {
    const int tid = threadIdx.x;
    const int g   = tid & 3;
    const int u   = tid >> 2;
    const int col = g * 128 + u;
    const int v0  = blockIdx.x * 16;

    __shared__ float elds[16 * EE];
    ((float4*)elds)[tid] = ((const float4*)(emb + (size_t)v0 * EE))[tid];
    __syncthreads();

    float bcol = bias[col];
    float acc[16];
#pragma unroll
    for (int r = 0; r < 16; ++r) acc[r] = bcol;

    const float4* elds4 = (const float4*)elds;
    for (int e0 = 0; e0 < EE; e0 += 4) {
        float k0 = wk[(e0 + 0) * G4 + col];
        float k1 = wk[(e0 + 1) * G4 + col];
        float k2 = wk[(e0 + 2) * G4 + col];
        float k3 = wk[(e0 + 3) * G4 + col];
#pragma unroll
        for (int r = 0; r < 16; ++r) {
            float4 ev = elds4[r * 32 + (e0 >> 2)];
            acc[r] = fmaf(ev.x, k0, acc[r]);
            acc[r] = fmaf(ev.y, k1, acc[r]);
            acc[r] = fmaf(ev.z, k2, acc[r]);
            acc[r] = fmaf(ev.w, k3, acc[r]);
        }
    }
#pragma unroll
    for (int r = 0; r < 16; ++r)
        P2[(size_t)(v0 + r) * G4 + tid] = acc[r];   // [v][u][g], coalesced
}

// ---------------------------------------------------------------------------
// Phase 2: sequential LSTM on the VALU with native packed-f16 FMA.
// Thread (u=tid>>2, q=tid&3): 32-dim h slice x 4 gate columns of unit u,
// weights = 64 resident f16x2 VGPRs (waves_per_eu(2,2) clamp -> proven
// resident in R9: VGPR=88, no remat/spill). Dots via v_pk_fma_f16
// (native 2 MAC/instr — R9's fdot2 was expanded, +375 cy/step), packed
// accumulators, packed quad butterfly (mov_dpp + v_pk_add_f16). Each lane
// horizontalizes only its own gate, activates it (2 trans), quad DPP
// broadcasts the 4 activations, redundant c/h update per quad.
// Depth-2 static P prefetch (gate-minor P2, scalar loads), tokens in LDS,
// lgkmcnt-only drain + raw s_barrier per step.
// ---------------------------------------------------------------------------
__global__ __launch_bounds__(512) __attribute__((amdgpu_waves_per_eu(2, 2)))
void lstm_kernel(
    const int* __restrict__ tokens, const float* __restrict__ rk,
    const float* __restrict__ P2, const float* __restrict__ dense_w,
    const float* __restrict__ dense_b, float* __restrict__ out) {
    const int tid = threadIdx.x;
    const int u   = tid >> 2;       // unit 0..127
    const int q   = tid & 3;        // slice & gate 0..3
    const int b   = blockIdx.x;

    __shared__ __align__(16) _Float16 hh[2][UU];   // double-buffered h (f16)
    __shared__ int   tokLDS[TT + 4];
    __shared__ float red[8];

    // ---- weights: wgt[g][p] = f16x2( rk[32q+2p][g*128+u], rk[32q+2p+1][..] )
    h2 wgt[4][16];
    const float* rkb = rk + (size_t)(32 * q) * G4;
#pragma unroll
    for (int g = 0; g < 4; ++g) {
        const int c = g * 128 + u;
#pragma unroll
        for (int p = 0; p < 16; ++p) {
            h2 hw;
            hw.x = (_Float16)rkb[(2 * p + 0) * G4 + c];
            hw.y = (_Float16)rkb[(2 * p + 1) * G4 + c];
            wgt[g][p] = hw;
        }
    }

    const int* trow = tokens + (size_t)b * TT;
    tokLDS[tid] = trow[tid];
    if (tid < 4) tokLDS[TT + tid] = trow[TT - 1];
    if (tid < UU) hh[0][tid] = (_Float16)0.f;      // h0 = 0

    const int pOff = 4 * u + q;                    // lane's dword in a P2 row
    float c_state = 0.f, hv = 0.f;
    float pf0 = P2[(size_t)trow[0] * G4 + pOff];
    float pf1 = P2[(size_t)trow[1] * G4 + pOff];
    __syncthreads();

    const h2 zzero = {(_Float16)0.f, (_Float16)0.f};

#define LSTEP(PAR, PF)                                                        \
    {                                                                         \
        int vtok = tokLDS[t + (PAR) + 2];                                     \
        float pcur = (PF);                       /* 2-step-old load */        \
        (PF) = P2[(size_t)vtok * G4 + pOff];     /* in flight ~2 steps */     \
        const int4* hrow = (const int4*)&hh[PAR][32 * q];                     \
        int4 hA = hrow[0], hB = hrow[1], hC = hrow[2], hD = hrow[3];          \
        h2 hr[16];                                                            \
        hr[0]  = __builtin_bit_cast(h2, hA.x);                                \
        hr[1]  = __builtin_bit_cast(h2, hA.y);                                \
        hr[2]  = __builtin_bit_cast(h2, hA.z);                                \
        hr[3]  = __builtin_bit_cast(h2, hA.w);                                \
        hr[4]  = __builtin_bit_cast(h2, hB.x);                                \
        hr[5]  = __builtin_bit_cast(h2, hB.y);                                \
        hr[6]  = __builtin_bit_cast(h2, hB.z);                                \
        hr[7]  = __builtin_bit_cast(h2, hB.w);                                \
        hr[8]  = __builtin_bit_cast(h2, hC.x);                                \
        hr[9]  = __builtin_bit_cast(h2, hC.y);                                \
        hr[10] = __builtin_bit_cast(h2, hC.z);                                \
        hr[11] = __builtin_bit_cast(h2, hC.w);                                \
        hr[12] = __builtin_bit_cast(h2, hD.x);                                \
        hr[13] = __builtin_bit_cast(h2, hD.y);                                \
        hr[14] = __builtin_bit_cast(h2, hD.z);                                \
        hr[15] = __builtin_bit_cast(h2, hD.w);                                \
        /* 8 packed-f16 accumulator chains (v_pk_fma_f16, 2 MAC each) */      \
        h2 a0[4], a1[4];                                                      \
        _Pragma("unroll")                                                     \
        for (int g = 0; g < 4; ++g) { a0[g] = zzero; a1[g] = zzero; }         \
        _Pragma("unroll")                                                     \
        for (int p = 0; p < 16; p += 2) {                                     \
            _Pragma("unroll")                                                 \
            for (int g = 0; g < 4; ++g) {                                     \
                a0[g] = hr[p] * wgt[g][p] + a0[g];                            \
                a1[g] = hr[p + 1] * wgt[g][p + 1] + a1[g];                    \
            }                                                                 \
        }                                                                     \
        /* packed quad butterfly: every lane gets packed full-sum per gate */ \
        h2 s0 = a0[0] + a1[0], s1 = a0[1] + a1[1];                            \
        h2 s2 = a0[2] + a1[2], s3 = a0[3] + a1[3];                            \
        s0 = pk_add_dpp(s0, 0xB1); s0 = pk_add_dpp(s0, 0x4E);                 \
        s1 = pk_add_dpp(s1, 0xB1); s1 = pk_add_dpp(s1, 0x4E);                 \
        s2 = pk_add_dpp(s2, 0xB1); s2 = pk_add_dpp(s2, 0x4E);                 \
        s3 = pk_add_dpp(s3, 0xB1); s3 = pk_add_dpp(s3, 0x4E);                 \
        /* lane q horizontalizes + activates only gate q (2 trans) */         \
        int ilo = (q & 1) ? __builtin_bit_cast(int, s1)                       \
                          : __builtin_bit_cast(int, s0);                      \
        int ihi = (q & 1) ? __builtin_bit_cast(int, s3)                       \
                          : __builtin_bit_cast(int, s2);                      \
        h2 own  = __builtin_bit_cast(h2, (q & 2) ? ihi : ilo);                \
        float zq = (float)own.x + (float)own.y + pcur;                        \
        float xs = (q == 2) ? zq + zq : zq;                                   \
        float sg = sigmoid_f(xs);                                             \
        float av = (q == 2) ? fmaf(2.f, sg, -1.f) : sg;                       \
        /* collect i,f,g,o via quad broadcasts */                             \
        float ai = dpp_f(av, 0x00);                                           \
        float af_ = dpp_f(av, 0x55);                                          \
        float ag = dpp_f(av, 0xAA);                                           \
        float ao = dpp_f(av, 0xFF);                                           \
        c_state = fmaf(af_, c_state, ai * ag);                                \
        hv      = ao * tanh_f(c_state);                                       \
        if (q == 0) hh[(PAR) ^ 1][u] = (_Float16)hv;                          \
        asm volatile("s_waitcnt lgkmcnt(0)" ::: "memory");                    \
        __builtin_amdgcn_s_barrier();                                         \
    }

    for (int t = 0; t < TT; t += 2) {
        LSTEP(0, pf0)
        LSTEP(1, pf1)
    }
#undef LSTEP

    // --- dense sigmoid head: out[b] = sigmoid(h @ w + b) ---
    float val = (q == 0) ? hv * dense_w[u] : 0.f;
#pragma unroll
    for (int off = 32; off > 0; off >>= 1) val += __shfl_xor(val, off, 64);
    if ((tid & 63) == 0) red[tid >> 6] = val;
    __syncthreads();
    if (tid == 0) {
        float s = dense_b[0];
#pragma unroll
        for (int i = 0; i < 8; ++i) s += red[i];
        out[b] = sigmoid_f(s);
    }
}

extern "C" void kernel_launch(void* const* d_in, const int* in_sizes, int n_in,
                              void* d_out, int out_size, void* d_ws, size_t ws_size,
                              hipStream_t stream) {
    const int*   tokens = (const int*)  d_in[0];
    const float* emb    = (const float*)d_in[1];
    const float* wk     = (const float*)d_in[2];
    const float* rk     = (const float*)d_in[3];
    const float* bias   = (const float*)d_in[4];
    const float* dw     = (const float*)d_in[5];
    const float* db     = (const float*)d_in[6];
    float* out = (float*)d_out;
    float* P2  = (float*)d_ws;     // 20000*512*4 = 40.96 MB scratch

    proj_kernel<<<VV / 16, 512, 0, stream>>>(emb, wk, bias, P2);
    lstm_kernel<<<BB, 512, 0, stream>>>(tokens, rk, P2, dw, db, out);
}